// Round 1
// baseline (63.112 us; speedup 1.0000x reference)
//
#include <hip/hip_runtime.h>

#define B_   2
#define H_   12
#define S_   512
#define D_   64
#define ALL_ 768

// d_out offsets (in floats), concatenated in reference return order
#define OFF_TN  0            // transformed_norm   [B,H,S]      12288
#define OFF_WN  12288        // weighted_norm      [B,H,S,S]    6291456
#define OFF_SWN 6303744      // summed_weighted_norm [B,S,S]    524288
#define OFF_T   6828032      // transformed        [B,H,S,ALL]  9437184

// ---------------------------------------------------------------------------
// Kernel A: per-head GEMM  T[b,h,s,e] = sum_d V[b,h,s,d] * W[e, h*64+d]
// grid (6 e-tiles, 8 r-tiles, 12 heads), block 256, tile 128x128, K=64 (2x32)
// LDS tiles stored transposed: As[k][row], Bs[k][e] so compute reads are
// broadcast (A) / dense-contiguous (B) float4s.
// ---------------------------------------------------------------------------
#define KSTR 132  // LDS row stride in words (128 + 4 pad, mult of 4 for b128)

__global__ __launch_bounds__(256) void kernelA(const float* __restrict__ V,
                                               const float* __restrict__ W,
                                               float* __restrict__ T) {
  __shared__ float As[32 * KSTR];
  __shared__ float Bs[32 * KSTR];
  const int tid = threadIdx.x;
  const int et = blockIdx.x, rt = blockIdx.y, h = blockIdx.z;
  const int tr = tid >> 4, tc = tid & 15;

  float acc[8][8] = {};

  for (int kk = 0; kk < 64; kk += 32) {
    if (kk) __syncthreads();
    // stage half-K tiles: 128 rows x 32 k each, as float4 along k
#pragma unroll
    for (int p = 0; p < 4; ++p) {
      int f = tid + (p << 8);          // 0..1023
      int row = f >> 3;                // 0..127
      int kw = (f & 7) << 2;           // 0,4,...,28
      int r = (rt << 7) + row;
      int b = r >> 9, s = r & 511;
      float4 va = *(const float4*)&V[((((b * H_ + h) << 9) + s) << 6) + kk + kw];
      As[(kw + 0) * KSTR + row] = va.x;
      As[(kw + 1) * KSTR + row] = va.y;
      As[(kw + 2) * KSTR + row] = va.z;
      As[(kw + 3) * KSTR + row] = va.w;
      int e = (et << 7) + row;
      float4 vb = *(const float4*)&W[e * ALL_ + (h << 6) + kk + kw];
      Bs[(kw + 0) * KSTR + row] = vb.x;
      Bs[(kw + 1) * KSTR + row] = vb.y;
      Bs[(kw + 2) * KSTR + row] = vb.z;
      Bs[(kw + 3) * KSTR + row] = vb.w;
    }
    __syncthreads();

#pragma unroll 4
    for (int k = 0; k < 32; ++k) {
      float4 a0 = *(const float4*)&As[k * KSTR + tr * 8];
      float4 a1 = *(const float4*)&As[k * KSTR + tr * 8 + 4];
      float4 b0 = *(const float4*)&Bs[k * KSTR + tc * 8];
      float4 b1 = *(const float4*)&Bs[k * KSTR + tc * 8 + 4];
      float av[8] = {a0.x, a0.y, a0.z, a0.w, a1.x, a1.y, a1.z, a1.w};
      float bv[8] = {b0.x, b0.y, b0.z, b0.w, b1.x, b1.y, b1.z, b1.w};
#pragma unroll
      for (int i = 0; i < 8; ++i)
#pragma unroll
        for (int j = 0; j < 8; ++j)
          acc[i][j] = fmaf(av[i], bv[j], acc[i][j]);
    }
  }

  // epilogue: coalesced float4 stores
#pragma unroll
  for (int i = 0; i < 8; ++i) {
    int r = (rt << 7) + tr * 8 + i;
    int b = r >> 9, s = r & 511;
    float* dst = T + (((b * H_ + h) << 9) + s) * ALL_ + (et << 7) + tc * 8;
    float4 o0 = {acc[i][0], acc[i][1], acc[i][2], acc[i][3]};
    float4 o1 = {acc[i][4], acc[i][5], acc[i][6], acc[i][7]};
    *(float4*)dst = o0;
    *(float4*)(dst + 4) = o1;
  }
}

// ---------------------------------------------------------------------------
// Kernel B: per (b,s): Gram G[h1,h2] = <t[b,h1,s,:], t[b,h2,s,:]> (144 vals)
// + transformed_norm from the diagonal. One block per (b,s), 256 threads.
// ---------------------------------------------------------------------------
#define TSTR 772  // 768 + 4 pad

__global__ __launch_bounds__(256) void kernelB(const float* __restrict__ T,
                                               float* __restrict__ TN,
                                               float* __restrict__ G) {
  __shared__ float Tl[12 * TSTR];
  const int tid = threadIdx.x;
  const int bs = blockIdx.x;          // 0..1023
  const int b = bs >> 9, s = bs & 511;

  // load t[12][768] (9216 floats = 2304 float4)
#pragma unroll
  for (int p = 0; p < 9; ++p) {
    int f = tid + (p << 8);           // 0..2303
    int h = f / 192;
    int e4 = (f % 192) << 2;
    float4 v = *(const float4*)&T[(((b * H_ + h) << 9) + s) * ALL_ + e4];
    *(float4*)&Tl[h * TSTR + e4] = v;
  }
  __syncthreads();

  if (tid < 144) {
    const int h1 = tid / 12, h2 = tid % 12;
    const float* x = Tl + h1 * TSTR;
    const float* y = Tl + h2 * TSTR;
    float acc = 0.f;
#pragma unroll 8
    for (int e = 0; e < ALL_; e += 4) {
      float4 xv = *(const float4*)(x + e);
      float4 yv = *(const float4*)(y + e);
      acc = fmaf(xv.x, yv.x, acc);
      acc = fmaf(xv.y, yv.y, acc);
      acc = fmaf(xv.z, yv.z, acc);
      acc = fmaf(xv.w, yv.w, acc);
    }
    G[bs * 144 + tid] = acc;
    if (h1 == h2) TN[(b * H_ + h1) * S_ + s] = sqrtf(acc);
  }
}

// ---------------------------------------------------------------------------
// Kernel C: weighted_norm[b,h,k,s] = |p| * tn[b,h,s]
//           summed_weighted_norm[b,k,s] = sqrt(p^T G[b,s] p)
// grid (8 s-tiles, 8 k-tiles, 2 b), block 256. G staged transposed in LDS.
// ---------------------------------------------------------------------------
#define GSTR 65

__global__ __launch_bounds__(256) void kernelC(const float* __restrict__ P,
                                               const float* __restrict__ G,
                                               float* __restrict__ WN,
                                               float* __restrict__ SWN) {
  __shared__ float Gl[144 * GSTR];
  __shared__ float TNl[12 * GSTR];
  const int tid = threadIdx.x;
  const int st = blockIdx.x, kt = blockIdx.y, b = blockIdx.z;
  const int s0 = st << 6, k0 = kt << 6;

  // stage G[b, s0..s0+63, 0..143] transposed -> Gl[j][sl]
#pragma unroll
  for (int p = 0; p < 9; ++p) {
    int f = tid + (p << 8);           // 0..2303
    int sl = f / 36;
    int j4 = (f % 36) << 2;
    float4 v = *(const float4*)&G[((b << 9) + s0 + sl) * 144 + j4];
    Gl[(j4 + 0) * GSTR + sl] = v.x;
    Gl[(j4 + 1) * GSTR + sl] = v.y;
    Gl[(j4 + 2) * GSTR + sl] = v.z;
    Gl[(j4 + 3) * GSTR + sl] = v.w;
  }
  __syncthreads();
  // per-head norms for this s-tile
#pragma unroll
  for (int p = 0; p < 3; ++p) {
    int f = tid + (p << 8);           // 0..767
    int h = f >> 6, sl = f & 63;
    TNl[h * GSTR + sl] = sqrtf(Gl[(h * 13) * GSTR + sl]);
  }
  __syncthreads();

  const int sl = tid & 63;
  const int kq = tid >> 6;            // 0..3
  const int s = s0 + sl;

#pragma unroll 1
  for (int kp = 0; kp < 16; ++kp) {
    const int k = k0 + (kp << 2) + kq;
    float pv[12];
#pragma unroll
    for (int h = 0; h < 12; ++h) {
      const int idx = (((b * H_ + h) << 9) + k) * S_ + s;
      pv[h] = P[idx];
      WN[idx] = fabsf(pv[h]) * TNl[h * GSTR + sl];
    }
    float q = 0.f;
#pragma unroll
    for (int h1 = 0; h1 < 12; ++h1) {
      q = fmaf(pv[h1] * pv[h1], Gl[(h1 * 13) * GSTR + sl], q);
#pragma unroll
      for (int h2 = h1 + 1; h2 < 12; ++h2)
        q = fmaf(2.f * pv[h1] * pv[h2], Gl[(h1 * 12 + h2) * GSTR + sl], q);
    }
    SWN[((b << 9) + k) * S_ + s] = sqrtf(fmaxf(q, 0.f));
  }
}

// ---------------------------------------------------------------------------
extern "C" void kernel_launch(void* const* d_in, const int* in_sizes, int n_in,
                              void* d_out, int out_size, void* d_ws, size_t ws_size,
                              hipStream_t stream) {
  // inputs: [0] hidden_states (unused), [1] attention_probs, [2] value_layer,
  //         [3] dense_weight — all float32
  const float* P = (const float*)d_in[1];
  const float* V = (const float*)d_in[2];
  const float* W = (const float*)d_in[3];
  float* out = (float*)d_out;
  float* G = (float*)d_ws;  // [B,S,144] = 589,824 bytes

  kernelA<<<dim3(6, 8, 12), 256, 0, stream>>>(V, W, out + OFF_T);
  kernelB<<<dim3(1024), 256, 0, stream>>>(out + OFF_T, out + OFF_TN, G);
  kernelC<<<dim3(8, 8, 2), 256, 0, stream>>>(P, G, out + OFF_WN, out + OFF_SWN);
}

// Round 2
// 53.419 us; speedup vs baseline: 1.1815x; 1.1815x over previous
//
#include <hip/hip_runtime.h>

#define B_   2
#define H_   12
#define S_   512
#define D_   64
#define ALL_ 768
#define NPAIR 78

// d_out offsets (in floats), concatenated in reference return order
#define OFF_TN  0            // transformed_norm   [B,H,S]      12288
#define OFF_WN  12288        // weighted_norm      [B,H,S,S]    6291456
#define OFF_SWN 6303744      // summed_weighted_norm [B,S,S]    524288
#define OFF_T   6828032      // transformed        [B,H,S,ALL]  9437184

// unique symmetric pair index (h1<=h2), p in [0,78)
__host__ __device__ constexpr int pairIdx(int h1, int h2) {
  return h1 * 12 - (h1 * (h1 - 1)) / 2 + (h2 - h1);
}

// ---------------------------------------------------------------------------
// Kernel A: per-head GEMM  T[b,h,s,e] = sum_d V[b,h,s,d] * W[e, h*64+d]
// tile 64 rows x 128 e, block 128 (8x16), micro 8x8, grid (6,16,12)=1152
// LDS k-major (transposed) tiles; B-tile e-index XOR-swizzled so the
// compute-phase ds_read_b128 (lanes tc,tc+4,tc+8,tc+12 were 32 words apart)
// is bank-conflict-free.
// ---------------------------------------------------------------------------
#define ASTR 68
#define BSTR 132

__global__ __launch_bounds__(128) void kernelA(const float* __restrict__ V,
                                               const float* __restrict__ W,
                                               float* __restrict__ T) {
  __shared__ float As[32 * ASTR];
  __shared__ float Bs[32 * BSTR];
  const int tid = threadIdx.x;
  const int et = blockIdx.x, rt = blockIdx.y, h = blockIdx.z;
  const int tr = tid >> 4, tc = tid & 15;
  // per-thread constant swizzled base for B reads: (tc*8) ^ (((tc*8)>>2)&24)
  const int bOff = (tc << 3) ^ (((tc << 3) >> 2) & 24);

  float acc[8][8] = {};

  for (int kk = 0; kk < 64; kk += 32) {
    if (kk) __syncthreads();
    // stage A half-tile: 64 rows x 32 k (512 float4)
#pragma unroll
    for (int p = 0; p < 4; ++p) {
      int f = tid + (p << 7);          // 0..511
      int row = f >> 3;                // 0..63
      int kw = (f & 7) << 2;           // 0,4,...,28
      int r = (rt << 6) + row;
      int b = r >> 9, s = r & 511;
      float4 va = *(const float4*)&V[((((b * H_ + h) << 9) + s) << 6) + kk + kw];
      As[(kw + 0) * ASTR + row] = va.x;
      As[(kw + 1) * ASTR + row] = va.y;
      As[(kw + 2) * ASTR + row] = va.z;
      As[(kw + 3) * ASTR + row] = va.w;
    }
    // stage B half-tile: 128 e x 32 k (1024 float4), swizzled e index
#pragma unroll
    for (int p = 0; p < 8; ++p) {
      int f = tid + (p << 7);          // 0..1023
      int e = f >> 3;                  // 0..127
      int kw = (f & 7) << 2;
      int es = e ^ ((e >> 2) & 24);    // XOR bits 3-4 with bits 5-6
      float4 vb = *(const float4*)&W[((et << 7) + e) * ALL_ + (h << 6) + kk + kw];
      Bs[(kw + 0) * BSTR + es] = vb.x;
      Bs[(kw + 1) * BSTR + es] = vb.y;
      Bs[(kw + 2) * BSTR + es] = vb.z;
      Bs[(kw + 3) * BSTR + es] = vb.w;
    }
    __syncthreads();

#pragma unroll 4
    for (int k = 0; k < 32; ++k) {
      float4 a0 = *(const float4*)&As[k * ASTR + tr * 8];
      float4 a1 = *(const float4*)&As[k * ASTR + tr * 8 + 4];
      float4 b0 = *(const float4*)&Bs[k * BSTR + bOff];
      float4 b1 = *(const float4*)&Bs[k * BSTR + (bOff ^ 4)];
      float av[8] = {a0.x, a0.y, a0.z, a0.w, a1.x, a1.y, a1.z, a1.w};
      // un-swizzle: bOff^4 delivers the (tc*8+4..7) chunk when bit2 of swz hit
      float bv[8] = {b0.x, b0.y, b0.z, b0.w, b1.x, b1.y, b1.z, b1.w};
#pragma unroll
      for (int i = 0; i < 8; ++i)
#pragma unroll
        for (int j = 0; j < 8; ++j)
          acc[i][j] = fmaf(av[i], bv[j], acc[i][j]);
    }
  }

#pragma unroll
  for (int i = 0; i < 8; ++i) {
    int r = (rt << 6) + tr * 8 + i;
    int b = r >> 9, s = r & 511;
    float* dst = T + (((b * H_ + h) << 9) + s) * ALL_ + (et << 7) + (tc << 3);
    float4 o0 = {acc[i][0], acc[i][1], acc[i][2], acc[i][3]};
    float4 o1 = {acc[i][4], acc[i][5], acc[i][6], acc[i][7]};
    *(float4*)dst = o0;
    *(float4*)(dst + 4) = o1;
  }
}

// ---------------------------------------------------------------------------
// Kernel B: one wave per (b,s). Lane l loads t[h][(64j+l)*4..+3] (float4,
// coalesced) for h=0..11, j=0..2; accumulates 78 unique pair dots in regs;
// 6-step shfl_xor butterfly; writes G_T[b][p][s] (+ transformed_norm from
// the diagonal). No LDS.
// ---------------------------------------------------------------------------
__global__ __launch_bounds__(256) void kernelB(const float* __restrict__ T,
                                               float* __restrict__ TN,
                                               float* __restrict__ GT) {
  const int tid = threadIdx.x;
  const int w = tid >> 6, lane = tid & 63;
  const int bs = (blockIdx.x << 2) + w;
  const int b = bs >> 9, s = bs & 511;

  float acc[NPAIR] = {};
#pragma unroll
  for (int j = 0; j < 3; ++j) {
    float4 tv[12];
#pragma unroll
    for (int h = 0; h < 12; ++h)
      tv[h] = *(const float4*)&T[(((b * H_ + h) << 9) + s) * ALL_ +
                                 (((j << 6) + lane) << 2)];
#pragma unroll
    for (int h1 = 0; h1 < 12; ++h1)
#pragma unroll
      for (int h2 = h1; h2 < 12; ++h2) {
        const int p = pairIdx(h1, h2);
        acc[p] = fmaf(tv[h1].x, tv[h2].x, acc[p]);
        acc[p] = fmaf(tv[h1].y, tv[h2].y, acc[p]);
        acc[p] = fmaf(tv[h1].z, tv[h2].z, acc[p]);
        acc[p] = fmaf(tv[h1].w, tv[h2].w, acc[p]);
      }
  }

#pragma unroll
  for (int p = 0; p < NPAIR; ++p) {
#pragma unroll
    for (int d = 1; d < 64; d <<= 1)
      acc[p] += __shfl_xor(acc[p], d, 64);
  }

  // lane l owns pair p=l (and p=64+l for l<14)
  {
    const int p = lane;
    const float v = acc[0];  // placeholder to keep structure; real below
  }
  // write owned pairs
  if (lane < 64) {
    const int p = lane;
    float v = 0.f;
    // select acc[p] with static unroll (runtime-index would go to scratch)
#pragma unroll
    for (int q = 0; q < NPAIR; ++q)
      if (q == p) v = acc[q];
    GT[(b * NPAIR + p) * S_ + s] = v;
#pragma unroll
    for (int h = 0; h < 12; ++h)
      if (p == pairIdx(h, h)) TN[(b * H_ + h) * S_ + s] = sqrtf(v);
  }
  if (lane < NPAIR - 64) {
    const int p = 64 + lane;
    float v = 0.f;
#pragma unroll
    for (int q = 64; q < NPAIR; ++q)
      if (q == p) v = acc[q];
    GT[(b * NPAIR + p) * S_ + s] = v;
#pragma unroll
    for (int h = 0; h < 12; ++h)
      if (p == pairIdx(h, h)) TN[(b * H_ + h) * S_ + s] = sqrtf(v);
  }
}

// ---------------------------------------------------------------------------
// Kernel C: weighted_norm[b,h,k,s] = |p| * tn[b,h,s]
//           summed_weighted_norm[b,k,s] = sqrt(p^T G p)
// No LDS: thread (sl,kq) loads its 78 G_T values coalesced along s into
// registers once, reuses across 16 k. grid (8 st, 32 kt, 2 b) = 512 blocks.
// ---------------------------------------------------------------------------
__global__ __launch_bounds__(256) void kernelC(const float* __restrict__ P,
                                               const float* __restrict__ GT,
                                               float* __restrict__ WN,
                                               float* __restrict__ SWN) {
  const int tid = threadIdx.x;
  const int st = blockIdx.x, kt = blockIdx.y, b = blockIdx.z;
  const int sl = tid & 63, kq = tid >> 6;
  const int s = (st << 6) + sl;

  float g[NPAIR];
#pragma unroll
  for (int p = 0; p < NPAIR; ++p)
    g[p] = GT[(b * NPAIR + p) * S_ + s];
  float tn[12];
#pragma unroll
  for (int h = 0; h < 12; ++h)
    tn[h] = sqrtf(g[pairIdx(h, h)]);

#pragma unroll 1
  for (int kp = 0; kp < 4; ++kp) {
    const int k = (kt << 4) + (kp << 2) + kq;
    float pv[12];
#pragma unroll
    for (int h = 0; h < 12; ++h) {
      const int idx = (((b * H_ + h) << 9) + k) * S_ + s;
      pv[h] = P[idx];
      WN[idx] = fabsf(pv[h]) * tn[h];
    }
    float q = 0.f;
#pragma unroll
    for (int h1 = 0; h1 < 12; ++h1) {
      q = fmaf(pv[h1] * pv[h1], g[pairIdx(h1, h1)], q);
#pragma unroll
      for (int h2 = h1 + 1; h2 < 12; ++h2)
        q = fmaf(2.f * pv[h1] * pv[h2], g[pairIdx(h1, h2)], q);
    }
    SWN[((b << 9) + k) * S_ + s] = sqrtf(fmaxf(q, 0.f));
  }
}

// ---------------------------------------------------------------------------
extern "C" void kernel_launch(void* const* d_in, const int* in_sizes, int n_in,
                              void* d_out, int out_size, void* d_ws, size_t ws_size,
                              hipStream_t stream) {
  const float* P = (const float*)d_in[1];
  const float* V = (const float*)d_in[2];
  const float* W = (const float*)d_in[3];
  float* out = (float*)d_out;
  float* GT = (float*)d_ws;  // [B][78][S] = 319,488 bytes

  kernelA<<<dim3(6, 16, 12), 128, 0, stream>>>(V, W, out + OFF_T);
  kernelB<<<dim3(256), 256, 0, stream>>>(out + OFF_T, out + OFF_TN, GT);
  kernelC<<<dim3(8, 32, 2), 256, 0, stream>>>(P, GT, out + OFF_WN, out + OFF_SWN);
}

// Round 3
// 42.694 us; speedup vs baseline: 1.4783x; 1.2512x over previous
//
#include <hip/hip_runtime.h>
#include <stdint.h>

#define B_   2
#define H_   12
#define S_   512
#define D_   64
#define ALL_ 768
#define NPAIR 78

// d_out offsets (in floats), concatenated in reference return order
#define OFF_TN  0            // transformed_norm   [B,H,S]      12288
#define OFF_WN  12288        // weighted_norm      [B,H,S,S]    6291456
#define OFF_SWN 6303744      // summed_weighted_norm [B,S,S]    524288
#define OFF_T   6828032      // transformed        [B,H,S,ALL]  9437184

typedef short short4v __attribute__((ext_vector_type(4)));
typedef short short8v __attribute__((ext_vector_type(8)));
typedef float f32x4  __attribute__((ext_vector_type(4)));

// unique symmetric pair index (h1<=h2), p in [0,78)
__host__ __device__ constexpr int pairIdx(int h1, int h2) {
  return h1 * 12 - (h1 * (h1 - 1)) / 2 + (h2 - h1);
}

__device__ inline short f2bf(float x) {
  union { float f; uint32_t u; } c; c.f = x;
  uint32_t r = (c.u + 0x7FFFu + ((c.u >> 16) & 1u)) >> 16;
  return (short)r;
}

// ---------------------------------------------------------------------------
// Kernel A (bf16 MFMA): T[b,h,s,e] = sum_d V[b,h,s,d] * W[e, h*64+d]
// tile 128 rows x 128 e, K=64 (2 MFMA k-steps), block 256 (4 waves),
// grid (6 et, 8 rt, 12 h) = 576. Staging converts f32->bf16 into LDS with
// XOR swizzle byte ^= (row&7)<<4 so ds_read_b128 frag reads are
// bank-conflict-free (each quarter-wave covers all 32 banks exactly 2x).
// Frag layouts: A a[j]=A[m=l&15][k=(l>>4)*8+j]; B b[j]=B[k][n=l&15];
// C/D col=l&15, row=(l>>4)*4+r  [m89].
// ---------------------------------------------------------------------------
__global__ __launch_bounds__(256) void kernelA(const float* __restrict__ V,
                                               const float* __restrict__ W,
                                               float* __restrict__ T) {
  __shared__ char Ab[128 * 128];   // [row][64 k] bf16, swizzled
  __shared__ char Bb[128 * 128];   // [e][64 k] bf16, swizzled
  const int tid = threadIdx.x;
  const int et = blockIdx.x, rt = blockIdx.y, h = blockIdx.z;

  // stage + convert: 2048 float4 each for A and B
#pragma unroll
  for (int p = 0; p < 8; ++p) {
    int f = tid + (p << 8);          // 0..2047
    int row = f >> 4, c = f & 15;    // k = 4c
    int addr = ((row << 7) + (c << 3)) ^ ((row & 7) << 4);
    int r = (rt << 7) + row;
    int b = r >> 9, s = r & 511;
    float4 v = *(const float4*)&V[((((b * H_ + h) << 9) + s) << 6) + (c << 2)];
    short4v sv = { f2bf(v.x), f2bf(v.y), f2bf(v.z), f2bf(v.w) };
    *(short4v*)(Ab + addr) = sv;
    float4 wv = *(const float4*)&W[((et << 7) + row) * ALL_ + (h << 6) + (c << 2)];
    short4v wsv = { f2bf(wv.x), f2bf(wv.y), f2bf(wv.z), f2bf(wv.w) };
    *(short4v*)(Bb + addr) = wsv;
  }
  __syncthreads();

  const int l = tid & 63, w = tid >> 6;
  const int lr = l & 15, lg = l >> 4;

  f32x4 acc[2][8];
#pragma unroll
  for (int i = 0; i < 2; ++i)
#pragma unroll
    for (int j = 0; j < 8; ++j) acc[i][j] = (f32x4){0.f, 0.f, 0.f, 0.f};

#pragma unroll
  for (int ks = 0; ks < 2; ++ks) {
    short8v a[2];
#pragma unroll
    for (int tm = 0; tm < 2; ++tm) {
      int row = (w << 5) + (tm << 4) + lr;
      int addr = ((row << 7) + (ks << 6) + (lg << 4)) ^ ((row & 7) << 4);
      a[tm] = *(short8v*)(Ab + addr);
    }
#pragma unroll
    for (int tn = 0; tn < 8; ++tn) {
      int row = (tn << 4) + lr;
      int addr = ((row << 7) + (ks << 6) + (lg << 4)) ^ ((row & 7) << 4);
      short8v bf = *(short8v*)(Bb + addr);
      acc[0][tn] = __builtin_amdgcn_mfma_f32_16x16x32_bf16(a[0], bf, acc[0][tn], 0, 0, 0);
      acc[1][tn] = __builtin_amdgcn_mfma_f32_16x16x32_bf16(a[1], bf, acc[1][tn], 0, 0, 0);
    }
  }

  // epilogue: lane writes col lr (+16*tn), rows (w*32 + tm*16 + lg*4 + r)
#pragma unroll
  for (int tm = 0; tm < 2; ++tm)
#pragma unroll
    for (int r = 0; r < 4; ++r) {
      int row = (w << 5) + (tm << 4) + (lg << 2) + r;
      int gr = (rt << 7) + row;
      int b = gr >> 9, s = gr & 511;
      float* dst = &T[(((b * H_ + h) << 9) + s) * ALL_ + (et << 7) + lr];
#pragma unroll
      for (int tn = 0; tn < 8; ++tn)
        dst[tn << 4] = acc[tm][tn][r];
    }
}

// ---------------------------------------------------------------------------
// Kernel B: one wave per (b,s). Lane l loads t[h][(64j+l)*4..+3] (float4,
// coalesced) for h=0..11, j=0..2; accumulates 78 unique pair dots in regs;
// 6-step shfl_xor butterfly; writes G_T[b][p][s] (+ transformed_norm from
// the diagonal). No LDS.
// ---------------------------------------------------------------------------
__global__ __launch_bounds__(256) void kernelB(const float* __restrict__ T,
                                               float* __restrict__ TN,
                                               float* __restrict__ GT) {
  const int tid = threadIdx.x;
  const int w = tid >> 6, lane = tid & 63;
  const int bs = (blockIdx.x << 2) + w;
  const int b = bs >> 9, s = bs & 511;

  float acc[NPAIR] = {};
#pragma unroll
  for (int j = 0; j < 3; ++j) {
    float4 tv[12];
#pragma unroll
    for (int h = 0; h < 12; ++h)
      tv[h] = *(const float4*)&T[(((b * H_ + h) << 9) + s) * ALL_ +
                                 (((j << 6) + lane) << 2)];
#pragma unroll
    for (int h1 = 0; h1 < 12; ++h1)
#pragma unroll
      for (int h2 = h1; h2 < 12; ++h2) {
        const int p = pairIdx(h1, h2);
        acc[p] = fmaf(tv[h1].x, tv[h2].x, acc[p]);
        acc[p] = fmaf(tv[h1].y, tv[h2].y, acc[p]);
        acc[p] = fmaf(tv[h1].z, tv[h2].z, acc[p]);
        acc[p] = fmaf(tv[h1].w, tv[h2].w, acc[p]);
      }
  }

#pragma unroll
  for (int p = 0; p < NPAIR; ++p) {
#pragma unroll
    for (int d = 1; d < 64; d <<= 1)
      acc[p] += __shfl_xor(acc[p], d, 64);
  }

  // lane l owns pair p=l (and p=64+l for l<14); static select avoids scratch
  if (lane < 64) {
    const int p = lane;
    float v = 0.f;
#pragma unroll
    for (int q = 0; q < NPAIR; ++q)
      if (q == p) v = acc[q];
    GT[(b * NPAIR + p) * S_ + s] = v;
#pragma unroll
    for (int h = 0; h < 12; ++h)
      if (p == pairIdx(h, h)) TN[(b * H_ + h) * S_ + s] = sqrtf(v);
  }
  if (lane < NPAIR - 64) {
    const int p = 64 + lane;
    float v = 0.f;
#pragma unroll
    for (int q = 64; q < NPAIR; ++q)
      if (q == p) v = acc[q];
    GT[(b * NPAIR + p) * S_ + s] = v;
#pragma unroll
    for (int h = 0; h < 12; ++h)
      if (p == pairIdx(h, h)) TN[(b * H_ + h) * S_ + s] = sqrtf(v);
  }
}

// ---------------------------------------------------------------------------
// Kernel C: weighted_norm[b,h,k,s] = |p| * tn[b,h,s]
//           summed_weighted_norm[b,k,s] = sqrt(p^T G p)
// No LDS: thread (sl,kq) loads its 78 G_T values coalesced along s into
// registers once, reuses across 16 k. grid (8 st, 32 kt, 2 b) = 512 blocks.
// ---------------------------------------------------------------------------
__global__ __launch_bounds__(256) void kernelC(const float* __restrict__ P,
                                               const float* __restrict__ GT,
                                               float* __restrict__ WN,
                                               float* __restrict__ SWN) {
  const int tid = threadIdx.x;
  const int st = blockIdx.x, kt = blockIdx.y, b = blockIdx.z;
  const int sl = tid & 63, kq = tid >> 6;
  const int s = (st << 6) + sl;

  float g[NPAIR];
#pragma unroll
  for (int p = 0; p < NPAIR; ++p)
    g[p] = GT[(b * NPAIR + p) * S_ + s];
  float tn[12];
#pragma unroll
  for (int h = 0; h < 12; ++h)
    tn[h] = sqrtf(g[pairIdx(h, h)]);

#pragma unroll 1
  for (int kp = 0; kp < 4; ++kp) {
    const int k = (kt << 4) + (kp << 2) + kq;
    float pv[12];
#pragma unroll
    for (int h = 0; h < 12; ++h) {
      const int idx = (((b * H_ + h) << 9) + k) * S_ + s;
      pv[h] = P[idx];
      WN[idx] = fabsf(pv[h]) * tn[h];
    }
    float q = 0.f;
#pragma unroll
    for (int h1 = 0; h1 < 12; ++h1) {
      q = fmaf(pv[h1] * pv[h1], g[pairIdx(h1, h1)], q);
#pragma unroll
      for (int h2 = h1 + 1; h2 < 12; ++h2)
        q = fmaf(2.f * pv[h1] * pv[h2], g[pairIdx(h1, h2)], q);
    }
    SWN[((b << 9) + k) * S_ + s] = sqrtf(fmaxf(q, 0.f));
  }
}

// ---------------------------------------------------------------------------
extern "C" void kernel_launch(void* const* d_in, const int* in_sizes, int n_in,
                              void* d_out, int out_size, void* d_ws, size_t ws_size,
                              hipStream_t stream) {
  const float* P = (const float*)d_in[1];
  const float* V = (const float*)d_in[2];
  const float* W = (const float*)d_in[3];
  float* out = (float*)d_out;
  float* GT = (float*)d_ws;  // [B][78][S] = 319,488 bytes

  kernelA<<<dim3(6, 8, 12), 256, 0, stream>>>(V, W, out + OFF_T);
  kernelB<<<dim3(256), 256, 0, stream>>>(out + OFF_T, out + OFF_TN, GT);
  kernelC<<<dim3(8, 32, 2), 256, 0, stream>>>(P, GT, out + OFF_WN, out + OFF_SWN);
}

// Round 4
// 40.235 us; speedup vs baseline: 1.5686x; 1.0611x over previous
//
#include <hip/hip_runtime.h>
#include <stdint.h>

#define B_   2
#define H_   12
#define S_   512
#define D_   64
#define ALL_ 768
#define NPAIR 78

// d_out offsets (in floats), concatenated in reference return order
#define OFF_TN  0            // transformed_norm   [B,H,S]      12288
#define OFF_WN  12288        // weighted_norm      [B,H,S,S]    6291456
#define OFF_SWN 6303744      // summed_weighted_norm [B,S,S]    524288
#define OFF_T   6828032      // transformed        [B,H,S,ALL]  9437184

typedef short short4v __attribute__((ext_vector_type(4)));
typedef short short8v __attribute__((ext_vector_type(8)));
typedef float f32x4  __attribute__((ext_vector_type(4)));

// unique symmetric pair index (h1<=h2), p in [0,78)
__host__ __device__ constexpr int pairIdx(int h1, int h2) {
  return h1 * 12 - (h1 * (h1 - 1)) / 2 + (h2 - h1);
}

__device__ inline short f2bf(float x) {
  union { float f; uint32_t u; } c; c.f = x;
  uint32_t r = (c.u + 0x7FFFu + ((c.u >> 16) & 1u)) >> 16;
  return (short)r;
}

// ---------------------------------------------------------------------------
// Kernel A (bf16 MFMA): T[b,h,s,e] = sum_d V[b,h,s,d] * W[e, h*64+d]
// tile 64 rows x 128 e, K=64 (2 MFMA k-steps), block 128 (2 waves),
// grid (6 et, 16 rt, 12 h) = 1152 blocks (4.5/CU, 11% tail vs 33% at 576).
// f32->bf16 staged into LDS with XOR swizzle byte ^= (row&7)<<4 so the
// ds_read_b128 fragment reads are 2-way (free) bank aliased.
// Frag layouts (validated r2): A a[j]=A[m=l&15][k=lg*8+j]; B b[j]=B[k][n=l&15];
// C/D col=l&15, row=lg*4+r  [m89].
// ---------------------------------------------------------------------------
__global__ __launch_bounds__(128) void kernelA(const float* __restrict__ V,
                                               const float* __restrict__ W,
                                               float* __restrict__ T) {
  __shared__ char Ab[64 * 128];    // [row][64 k] bf16, swizzled
  __shared__ char Bb[128 * 128];   // [e][64 k] bf16, swizzled
  const int tid = threadIdx.x;
  const int et = blockIdx.x, rt = blockIdx.y, h = blockIdx.z;

  // stage A: 64 rows x 16 float4-chunks = 1024 tasks
#pragma unroll
  for (int p = 0; p < 8; ++p) {
    int f = tid + (p << 7);          // 0..1023
    int row = f >> 4, c = f & 15;    // k = 4c
    int addr = ((row << 7) + (c << 3)) ^ ((row & 7) << 4);
    int r = (rt << 6) + row;
    int b = r >> 9, s = r & 511;
    float4 v = *(const float4*)&V[((((b * H_ + h) << 9) + s) << 6) + (c << 2)];
    short4v sv = { f2bf(v.x), f2bf(v.y), f2bf(v.z), f2bf(v.w) };
    *(short4v*)(Ab + addr) = sv;
  }
  // stage B: 128 e-rows x 16 chunks = 2048 tasks
#pragma unroll
  for (int p = 0; p < 16; ++p) {
    int f = tid + (p << 7);          // 0..2047
    int row = f >> 4, c = f & 15;
    int addr = ((row << 7) + (c << 3)) ^ ((row & 7) << 4);
    float4 wv = *(const float4*)&W[((et << 7) + row) * ALL_ + (h << 6) + (c << 2)];
    short4v wsv = { f2bf(wv.x), f2bf(wv.y), f2bf(wv.z), f2bf(wv.w) };
    *(short4v*)(Bb + addr) = wsv;
  }
  __syncthreads();

  const int l = tid & 63, w = tid >> 6;
  const int lr = l & 15, lg = l >> 4;

  f32x4 acc[2][8];
#pragma unroll
  for (int i = 0; i < 2; ++i)
#pragma unroll
    for (int j = 0; j < 8; ++j) acc[i][j] = (f32x4){0.f, 0.f, 0.f, 0.f};

#pragma unroll
  for (int ks = 0; ks < 2; ++ks) {
    short8v a[2];
#pragma unroll
    for (int tm = 0; tm < 2; ++tm) {
      int row = (w << 5) + (tm << 4) + lr;
      int addr = ((row << 7) + (ks << 6) + (lg << 4)) ^ ((row & 7) << 4);
      a[tm] = *(short8v*)(Ab + addr);
    }
#pragma unroll
    for (int tn = 0; tn < 8; ++tn) {
      int row = (tn << 4) + lr;
      int addr = ((row << 7) + (ks << 6) + (lg << 4)) ^ ((row & 7) << 4);
      short8v bf = *(short8v*)(Bb + addr);
      acc[0][tn] = __builtin_amdgcn_mfma_f32_16x16x32_bf16(a[0], bf, acc[0][tn], 0, 0, 0);
      acc[1][tn] = __builtin_amdgcn_mfma_f32_16x16x32_bf16(a[1], bf, acc[1][tn], 0, 0, 0);
    }
  }

  // epilogue: lane writes col lr (+16*tn), rows (w*32 + tm*16 + lg*4 + r)
#pragma unroll
  for (int tm = 0; tm < 2; ++tm)
#pragma unroll
    for (int r = 0; r < 4; ++r) {
      int row = (w << 5) + (tm << 4) + (lg << 2) + r;
      int gr = (rt << 6) + row;
      int b = gr >> 9, s = gr & 511;
      float* dst = &T[(((b * H_ + h) << 9) + s) * ALL_ + (et << 7) + lr];
#pragma unroll
      for (int tn = 0; tn < 8; ++tn)
        dst[tn << 4] = acc[tm][tn][r];
    }
}

// ---------------------------------------------------------------------------
// Kernel B (MFMA Gram): one wave per (b,s). X = T[b,:,s,:] (12x768, pad 16).
// Key trick: for 16x16x32 bf16 the B-fragment of X^T equals the A-fragment
// of X (b[j]=B[k][n=l&15]=X[l&15][k]=a[j]) -> G = mfma(x, x, acc) over 24
// k-steps. Lane (row<=col<12) writes GT[b][pair][s]; diagonal writes TN.
// Serial chain ~24 dependent MFMAs; T is L3-resident (37.7 MB).
// ---------------------------------------------------------------------------
__global__ __launch_bounds__(256) void kernelB(const float* __restrict__ T,
                                               float* __restrict__ TN,
                                               float* __restrict__ GT) {
  const int tid = threadIdx.x;
  const int w = tid >> 6, l = tid & 63;
  const int bs = (blockIdx.x << 2) + w;
  const int b = bs >> 9, s = bs & 511;
  const int col = l & 15, lg = l >> 4;

  const float* rowp = T + (((b * H_ + col) << 9) + s) * ALL_;  // h = col
  const bool act = col < 12;

  f32x4 acc = (f32x4){0.f, 0.f, 0.f, 0.f};
#pragma unroll
  for (int kk = 0; kk < 24; ++kk) {
    const int e = (kk << 5) + (lg << 3);
    short8v x = (short8v){0, 0, 0, 0, 0, 0, 0, 0};
    if (act) {
      float4 u0 = *(const float4*)(rowp + e);
      float4 u1 = *(const float4*)(rowp + e + 4);
      x = (short8v){f2bf(u0.x), f2bf(u0.y), f2bf(u0.z), f2bf(u0.w),
                    f2bf(u1.x), f2bf(u1.y), f2bf(u1.z), f2bf(u1.w)};
    }
    acc = __builtin_amdgcn_mfma_f32_16x16x32_bf16(x, x, acc, 0, 0, 0);
  }

#pragma unroll
  for (int r = 0; r < 4; ++r) {
    const int rw = (lg << 2) + r;     // Gram row
    const float v = acc[r];
    if (col < 12 && rw <= col) {
      const int p = rw * 12 - (rw * (rw - 1)) / 2 + (col - rw);
      GT[(b * NPAIR + p) * S_ + s] = v;
      if (rw == col) TN[(b * H_ + col) * S_ + s] = sqrtf(v);
    }
  }
}

// ---------------------------------------------------------------------------
// Kernel C: weighted_norm[b,h,k,s] = |p| * tn[b,h,s]
//           summed_weighted_norm[b,k,s] = sqrt(p^T G p)
// No LDS: thread (sl,kq) loads its 78 G_T values coalesced along s into
// registers once, reuses across 16 k. grid (8 st, 32 kt, 2 b) = 512 blocks.
// ---------------------------------------------------------------------------
__global__ __launch_bounds__(256) void kernelC(const float* __restrict__ P,
                                               const float* __restrict__ GT,
                                               float* __restrict__ WN,
                                               float* __restrict__ SWN) {
  const int tid = threadIdx.x;
  const int st = blockIdx.x, kt = blockIdx.y, b = blockIdx.z;
  const int sl = tid & 63, kq = tid >> 6;
  const int s = (st << 6) + sl;

  float g[NPAIR];
#pragma unroll
  for (int p = 0; p < NPAIR; ++p)
    g[p] = GT[(b * NPAIR + p) * S_ + s];
  float tn[12];
#pragma unroll
  for (int h = 0; h < 12; ++h)
    tn[h] = sqrtf(g[pairIdx(h, h)]);

#pragma unroll 1
  for (int kp = 0; kp < 4; ++kp) {
    const int k = (kt << 4) + (kp << 2) + kq;
    float pv[12];
#pragma unroll
    for (int h = 0; h < 12; ++h) {
      const int idx = (((b * H_ + h) << 9) + k) * S_ + s;
      pv[h] = P[idx];
      WN[idx] = fabsf(pv[h]) * tn[h];
    }
    float q = 0.f;
#pragma unroll
    for (int h1 = 0; h1 < 12; ++h1) {
      q = fmaf(pv[h1] * pv[h1], g[pairIdx(h1, h1)], q);
#pragma unroll
      for (int h2 = h1 + 1; h2 < 12; ++h2)
        q = fmaf(2.f * pv[h1] * pv[h2], g[pairIdx(h1, h2)], q);
    }
    SWN[((b << 9) + k) * S_ + s] = sqrtf(fmaxf(q, 0.f));
  }
}

// ---------------------------------------------------------------------------
extern "C" void kernel_launch(void* const* d_in, const int* in_sizes, int n_in,
                              void* d_out, int out_size, void* d_ws, size_t ws_size,
                              hipStream_t stream) {
  const float* P = (const float*)d_in[1];
  const float* V = (const float*)d_in[2];
  const float* W = (const float*)d_in[3];
  float* out = (float*)d_out;
  float* GT = (float*)d_ws;  // [B][78][S] = 319,488 bytes

  kernelA<<<dim3(6, 16, 12), 128, 0, stream>>>(V, W, out + OFF_T);
  kernelB<<<dim3(256), 256, 0, stream>>>(out + OFF_T, out + OFF_TN, GT);
  kernelC<<<dim3(8, 32, 2), 256, 0, stream>>>(P, GT, out + OFF_WN, out + OFF_SWN);
}

// Round 5
// 39.782 us; speedup vs baseline: 1.5865x; 1.0114x over previous
//
#include <hip/hip_runtime.h>
#include <stdint.h>

#define B_   2
#define H_   12
#define S_   512
#define D_   64
#define ALL_ 768
#define NPAIR 78

// d_out offsets (in floats), concatenated in reference return order
#define OFF_TN  0            // transformed_norm   [B,H,S]      12288
#define OFF_WN  12288        // weighted_norm      [B,H,S,S]    6291456
#define OFF_SWN 6303744      // summed_weighted_norm [B,S,S]    524288
#define OFF_T   6828032      // transformed        [B,H,S,ALL]  9437184

typedef short short4v __attribute__((ext_vector_type(4)));
typedef short short8v __attribute__((ext_vector_type(8)));
typedef float f32x4  __attribute__((ext_vector_type(4)));

// unique symmetric pair index (h1<=h2), p in [0,78)
__host__ __device__ constexpr int pairIdx(int h1, int h2) {
  return h1 * 12 - (h1 * (h1 - 1)) / 2 + (h2 - h1);
}

__device__ inline short f2bf(float x) {
  union { float f; uint32_t u; } c; c.f = x;
  uint32_t r = (c.u + 0x7FFFu + ((c.u >> 16) & 1u)) >> 16;
  return (short)r;
}

// ---------------------------------------------------------------------------
// Kernel A (bf16 MFMA): T[b,h,s,e] = sum_d V[b,h,s,d] * W[e, h*64+d]
// tile 64 rows x 128 e, K=64 (2 MFMA k-steps), block 128 (2 waves),
// grid (6 et, 16 rt, 12 h) = 1152.
// A-fragments load DIRECT from global (8 consecutive d of one V row =
// 2 float4 + cvt) — no LDS for A. W staged f32->bf16 in LDS with XOR
// swizzle byte ^= (row&7)<<4 (ds_read_b128 2-way aliased = free).
// Frag layouts (validated r2/r3): A a[j]=A[m=l&15][k=lg*8+j];
// B b[j]=B[k][n=l&15]; C/D col=l&15, row=lg*4+r  [m89].
// ---------------------------------------------------------------------------
__global__ __launch_bounds__(128) void kernelA(const float* __restrict__ V,
                                               const float* __restrict__ W,
                                               float* __restrict__ T) {
  __shared__ char Bb[128 * 128];   // [e][64 k] bf16, swizzled
  const int tid = threadIdx.x;
  const int et = blockIdx.x, rt = blockIdx.y, h = blockIdx.z;

  // stage W: 128 e-rows x 16 float4-chunks = 2048 tasks (16/thread)
#pragma unroll
  for (int p = 0; p < 16; ++p) {
    int f = tid + (p << 7);          // 0..2047
    int row = f >> 4, c = f & 15;    // k = 4c
    int addr = ((row << 7) + (c << 3)) ^ ((row & 7) << 4);
    float4 wv = *(const float4*)&W[((et << 7) + row) * ALL_ + (h << 6) + (c << 2)];
    short4v wsv = { f2bf(wv.x), f2bf(wv.y), f2bf(wv.z), f2bf(wv.w) };
    *(short4v*)(Bb + addr) = wsv;
  }

  const int l = tid & 63, w = tid >> 6;
  const int lr = l & 15, lg = l >> 4;

  // A-fragments direct from global: lane reads V[row][ks*32 + lg*8 .. +7]
  short8v a[2][2];  // [ks][tm]
#pragma unroll
  for (int ks = 0; ks < 2; ++ks)
#pragma unroll
    for (int tm = 0; tm < 2; ++tm) {
      int row = (w << 5) + (tm << 4) + lr;
      int gr = (rt << 6) + row;
      int b = gr >> 9, s = gr & 511;
      const float* src = &V[((((b * H_ + h) << 9) + s) << 6) + (ks << 5) + (lg << 3)];
      float4 u0 = *(const float4*)src;
      float4 u1 = *(const float4*)(src + 4);
      a[ks][tm] = (short8v){f2bf(u0.x), f2bf(u0.y), f2bf(u0.z), f2bf(u0.w),
                            f2bf(u1.x), f2bf(u1.y), f2bf(u1.z), f2bf(u1.w)};
    }
  __syncthreads();

  f32x4 acc[2][8];
#pragma unroll
  for (int i = 0; i < 2; ++i)
#pragma unroll
    for (int j = 0; j < 8; ++j) acc[i][j] = (f32x4){0.f, 0.f, 0.f, 0.f};

#pragma unroll
  for (int ks = 0; ks < 2; ++ks)
#pragma unroll
    for (int tn = 0; tn < 8; ++tn) {
      int row = (tn << 4) + lr;
      int addr = ((row << 7) + (ks << 6) + (lg << 4)) ^ ((row & 7) << 4);
      short8v bf = *(short8v*)(Bb + addr);
      acc[0][tn] = __builtin_amdgcn_mfma_f32_16x16x32_bf16(a[ks][0], bf, acc[0][tn], 0, 0, 0);
      acc[1][tn] = __builtin_amdgcn_mfma_f32_16x16x32_bf16(a[ks][1], bf, acc[1][tn], 0, 0, 0);
    }

  // epilogue: lane writes col lr (+16*tn), rows (w*32 + tm*16 + lg*4 + r)
#pragma unroll
  for (int tm = 0; tm < 2; ++tm)
#pragma unroll
    for (int r = 0; r < 4; ++r) {
      int row = (w << 5) + (tm << 4) + (lg << 2) + r;
      int gr = (rt << 6) + row;
      int b = gr >> 9, s = gr & 511;
      float* dst = &T[(((b * H_ + h) << 9) + s) * ALL_ + (et << 7) + lr];
#pragma unroll
      for (int tn = 0; tn < 8; ++tn)
        dst[tn << 4] = acc[tm][tn][r];
    }
}

// ---------------------------------------------------------------------------
// Kernel B (MFMA Gram): one wave per (b,s). X = T[b,:,s,:] (12x768, pad 16).
// B-fragment of X^T equals A-fragment of X -> G = mfma(x, x, acc) over 24
// k-steps. Lane (row<=col<12) writes GT[b][pair][s]; diagonal writes TN.
// ---------------------------------------------------------------------------
__global__ __launch_bounds__(256) void kernelB(const float* __restrict__ T,
                                               float* __restrict__ TN,
                                               float* __restrict__ GT) {
  const int tid = threadIdx.x;
  const int w = tid >> 6, l = tid & 63;
  const int bs = (blockIdx.x << 2) + w;
  const int b = bs >> 9, s = bs & 511;
  const int col = l & 15, lg = l >> 4;

  const float* rowp = T + (((b * H_ + col) << 9) + s) * ALL_;  // h = col
  const bool act = col < 12;

  f32x4 acc = (f32x4){0.f, 0.f, 0.f, 0.f};
#pragma unroll
  for (int kk = 0; kk < 24; ++kk) {
    const int e = (kk << 5) + (lg << 3);
    short8v x = (short8v){0, 0, 0, 0, 0, 0, 0, 0};
    if (act) {
      float4 u0 = *(const float4*)(rowp + e);
      float4 u1 = *(const float4*)(rowp + e + 4);
      x = (short8v){f2bf(u0.x), f2bf(u0.y), f2bf(u0.z), f2bf(u0.w),
                    f2bf(u1.x), f2bf(u1.y), f2bf(u1.z), f2bf(u1.w)};
    }
    acc = __builtin_amdgcn_mfma_f32_16x16x32_bf16(x, x, acc, 0, 0, 0);
  }

#pragma unroll
  for (int r = 0; r < 4; ++r) {
    const int rw = (lg << 2) + r;     // Gram row
    const float v = acc[r];
    if (col < 12 && rw <= col) {
      const int p = rw * 12 - (rw * (rw - 1)) / 2 + (col - rw);
      GT[(b * NPAIR + p) * S_ + s] = v;
      if (rw == col) TN[(b * H_ + col) * S_ + s] = sqrtf(v);
    }
  }
}

// ---------------------------------------------------------------------------
// Kernel C: weighted_norm[b,h,k,s] = |p| * tn[b,h,s]
//           summed_weighted_norm[b,k,s] = sqrt(p^T G p)
// grid (8 st, 32 kt, 2 b) = 512 blocks. g[78] in registers, reused over 16 k.
// kp loop fully unrolled: all 48 P-loads batched ahead of compute for MLP.
// ---------------------------------------------------------------------------
__global__ __launch_bounds__(256) void kernelC(const float* __restrict__ P,
                                               const float* __restrict__ GT,
                                               float* __restrict__ WN,
                                               float* __restrict__ SWN) {
  const int tid = threadIdx.x;
  const int st = blockIdx.x, kt = blockIdx.y, b = blockIdx.z;
  const int sl = tid & 63, kq = tid >> 6;
  const int s = (st << 6) + sl;

  float g[NPAIR];
#pragma unroll
  for (int p = 0; p < NPAIR; ++p)
    g[p] = GT[(b * NPAIR + p) * S_ + s];
  float tn[12];
#pragma unroll
  for (int h = 0; h < 12; ++h)
    tn[h] = sqrtf(g[pairIdx(h, h)]);

  // batch all P loads (4 kp x 12 h) for memory-level parallelism
  float pv[4][12];
#pragma unroll
  for (int kp = 0; kp < 4; ++kp) {
    const int k = (kt << 4) + (kp << 2) + kq;
#pragma unroll
    for (int h = 0; h < 12; ++h)
      pv[kp][h] = P[(((b * H_ + h) << 9) + k) * S_ + s];
  }

#pragma unroll
  for (int kp = 0; kp < 4; ++kp) {
    const int k = (kt << 4) + (kp << 2) + kq;
#pragma unroll
    for (int h = 0; h < 12; ++h) {
      const int idx = (((b * H_ + h) << 9) + k) * S_ + s;
      WN[idx] = fabsf(pv[kp][h]) * tn[h];
    }
    float q = 0.f;
#pragma unroll
    for (int h1 = 0; h1 < 12; ++h1) {
      q = fmaf(pv[kp][h1] * pv[kp][h1], g[pairIdx(h1, h1)], q);
#pragma unroll
      for (int h2 = h1 + 1; h2 < 12; ++h2)
        q = fmaf(2.f * pv[kp][h1] * pv[kp][h2], g[pairIdx(h1, h2)], q);
    }
    SWN[((b << 9) + k) * S_ + s] = sqrtf(fmaxf(q, 0.f));
  }
}

// ---------------------------------------------------------------------------
extern "C" void kernel_launch(void* const* d_in, const int* in_sizes, int n_in,
                              void* d_out, int out_size, void* d_ws, size_t ws_size,
                              hipStream_t stream) {
  const float* P = (const float*)d_in[1];
  const float* V = (const float*)d_in[2];
  const float* W = (const float*)d_in[3];
  float* out = (float*)d_out;
  float* GT = (float*)d_ws;  // [B][78][S] = 319,488 bytes

  kernelA<<<dim3(6, 16, 12), 128, 0, stream>>>(V, W, out + OFF_T);
  kernelB<<<dim3(256), 256, 0, stream>>>(out + OFF_T, out + OFF_TN, GT);
  kernelC<<<dim3(8, 32, 2), 256, 0, stream>>>(P, GT, out + OFF_WN, out + OFF_SWN);
}